// Round 1
// baseline (415.463 us; speedup 1.0000x reference)
//
#include <hip/hip_runtime.h>
#include <stdint.h>
#include <stddef.h>

typedef short s8v   __attribute__((ext_vector_type(8)));  // 8 bf16 (4 VGPRs)
typedef float f32x4 __attribute__((ext_vector_type(4)));

union BF8 { s8v v; unsigned short u[8]; };

__device__ __forceinline__ float bf16_f(unsigned short h) {
  unsigned u = ((unsigned)h) << 16;
  return __builtin_bit_cast(float, u);
}
// truncation split: h = top16(x), residual exact (Sterbenz), l = top16(resid)
__device__ __forceinline__ void split_trunc(float x, unsigned short &h, unsigned short &l) {
  unsigned u = __builtin_bit_cast(unsigned, x);
  h = (unsigned short)(u >> 16);
  float hi = __builtin_bit_cast(float, u & 0xFFFF0000u);
  float r = x - hi;
  l = (unsigned short)(__builtin_bit_cast(unsigned, r) >> 16);
}
__device__ __forceinline__ f32x4 mfma16(s8v a, s8v b, f32x4 c) {
  return __builtin_amdgcn_mfma_f32_16x16x32_bf16(a, b, c, 0, 0, 0);
}
__device__ __forceinline__ void split8(f32x4 a, f32x4 b, s8v &h, s8v &l) {
  BF8 hh, ll;
  #pragma unroll
  for (int i = 0; i < 4; ++i) { split_trunc(a[i], hh.u[i], ll.u[i]); split_trunc(b[i], hh.u[4 + i], ll.u[4 + i]); }
  h = hh.v; l = ll.v;
}

#define BATCH 64
#define NN    4096
#define NX    128
#define NU    32
#define NY    32
#define LPAD  132   // LDS row stride in shorts (bank-conflict tuned)
#define CH    32    // chunk length (was 64): 2x blocks, half serial depth
#define CPB   128   // chunks per batch

// ---------------- workspace byte offsets ----------------
#define OFF_AH   0
#define OFF_AL   32768
#define OFF_BH   65536
#define OFF_BL   73728
#define OFF_CH   81920
#define OFF_CL   90112
#define OFF_DH   98304
#define OFF_DL   100352
#define OFF_A2H  102400
#define OFF_A2L  135168
#define OFF_ABH  167936
#define OFF_ABL  176128
#define OFF_G1H  184320
#define OFF_G1L  217088
#define OFF_G2H  249856
#define OFF_G2L  282624
#define OFF_G3H  315392
#define OFF_G3L  348160
#define OFF_P0   380928
#define OFF_P1   446464
#define OFF_V    512000
#define OFF_S    4706304
// end 8900608 (~8.5 MB)

// ---------------- fused: A*A (fp32 + hi/lo) and split A,B,C,D ----------------
__global__ void k_mm_conv(const float* __restrict__ A, const float* __restrict__ B,
                          const float* __restrict__ C, const float* __restrict__ D,
                          float* __restrict__ P, unsigned short* A2h, unsigned short* A2l,
                          unsigned short* Ah, unsigned short* Al,
                          unsigned short* Bh, unsigned short* Bl,
                          unsigned short* Ch, unsigned short* Cl,
                          unsigned short* Dh, unsigned short* Dl) {
  int gid = blockIdx.x * 256 + threadIdx.x;
  if (blockIdx.x < 64) {               // A^2
    int row = gid >> 7, col = gid & 127;
    const float* xr = A + row * 128;
    float a0 = 0.f, a1 = 0.f;
    #pragma unroll 8
    for (int k = 0; k < 128; k += 2) {
      a0 = fmaf(xr[k],     A[k * 128 + col],       a0);
      a1 = fmaf(xr[k + 1], A[(k + 1) * 128 + col], a1);
    }
    float acc = a0 + a1;
    P[gid] = acc;
    unsigned short h, l; split_trunc(acc, h, l);
    A2h[gid] = h; A2l[gid] = l;
  } else {                             // convert
    int idx = gid - 16384;
    unsigned short h, l;
    if (idx < 16384)      { split_trunc(A[idx], h, l); Ah[idx] = h; Al[idx] = l; }
    else if (idx < 20480) { int i = idx - 16384; split_trunc(B[i], h, l); Bh[i] = h; Bl[i] = l; }
    else if (idx < 24576) { int i = idx - 20480; split_trunc(C[i], h, l); Ch[i] = h; Cl[i] = l; }
    else if (idx < 25600) { int i = idx - 24576; split_trunc(D[i], h, l); Dh[i] = h; Dl[i] = l; }
  }
}

// ---------------- 128x128 fp32 matmul (powers chain) ----------------
__global__ void k_mm128(const float* __restrict__ X, const float* __restrict__ Y,
                        float* __restrict__ Z, unsigned short* Zh, unsigned short* Zl,
                        int writeBF) {
  int gid = blockIdx.x * 256 + threadIdx.x;
  int row = gid >> 7, col = gid & 127;
  const float* xr = X + row * 128;
  float a0 = 0.f, a1 = 0.f;
  #pragma unroll 8
  for (int k = 0; k < 128; k += 2) {
    a0 = fmaf(xr[k],     Y[k * 128 + col],       a0);
    a1 = fmaf(xr[k + 1], Y[(k + 1) * 128 + col], a1);
  }
  float acc = a0 + a1;
  Z[gid] = acc;
  if (writeBF) { unsigned short h, l; split_trunc(acc, h, l); Zh[gid] = h; Zl[gid] = l; }
}

// ---------------- AB = A*B [128x32] (hi/lo) ----------------
__global__ void k_ab(const float* __restrict__ A, const float* __restrict__ B,
                     unsigned short* ABh, unsigned short* ABl) {
  int gid = blockIdx.x * 256 + threadIdx.x;   // 16 blocks -> 4096
  int row = gid >> 5, col = gid & 31;
  float acc = 0.f;
  #pragma unroll 8
  for (int k = 0; k < 128; ++k) acc = fmaf(A[row * 128 + k], B[k * 32 + col], acc);
  unsigned short h, l; split_trunc(acc, h, l);
  ABh[gid] = h; ABl[gid] = l;
}

// ---------------- pass 1: step-2 local chunk scans (x0=0) -> v_c = X_32 ----------------
__global__ __launch_bounds__(256, 2) void k_pass1(
    const float* __restrict__ d,
    const unsigned short* __restrict__ A2h, const unsigned short* __restrict__ A2l,
    const unsigned short* __restrict__ ABh, const unsigned short* __restrict__ ABl,
    const unsigned short* __restrict__ Bh,  const unsigned short* __restrict__ Bl,
    float* __restrict__ vout) {
  __shared__ unsigned short Xh[2][16][LPAD];
  __shared__ unsigned short Xl[2][16][LPAD];
  const int tid = threadIdx.x;
  const int w = tid >> 6, l = tid & 63, q = l >> 4, m = l & 15;
  const int g = blockIdx.x;

  s8v fA2h[2][4], fA2l[2][4], fABh[2], fABl[2], fBh[2], fBl[2];
  #pragma unroll
  for (int t2 = 0; t2 < 2; ++t2) {
    const int n = (2 * w + t2) * 16 + m;
    #pragma unroll
    for (int kt = 0; kt < 4; ++kt) {
      const int k0 = kt * 32 + q * 8;
      fA2h[t2][kt] = *(const s8v*)(A2h + n * 128 + k0);
      fA2l[t2][kt] = *(const s8v*)(A2l + n * 128 + k0);
    }
    fABh[t2] = *(const s8v*)(ABh + n * 32 + q * 8);
    fABl[t2] = *(const s8v*)(ABl + n * 32 + q * 8);
    fBh[t2]  = *(const s8v*)(Bh  + n * 32 + q * 8);
    fBl[t2]  = *(const s8v*)(Bl  + n * 32 + q * 8);
  }
  for (int i = tid; i < 16 * LPAD; i += 256) {
    ((unsigned short*)Xh[0])[i] = 0;
    ((unsigned short*)Xl[0])[i] = 0;
  }
  __syncthreads();

  const int ch = g * 16 + m, b = ch >> 7, chunk = ch & (CPB - 1);
  const float* ubase = d + ((size_t)b * NN + chunk * CH) * NU + q * 8;

  f32x4 cu[4];
  cu[0] = *(const f32x4*)(ubase);      cu[1] = *(const f32x4*)(ubase + 4);
  cu[2] = *(const f32x4*)(ubase + 32); cu[3] = *(const f32x4*)(ubase + 36);

  f32x4 acc[2];
  #pragma unroll 2
  for (int r = 0; r < 16; ++r) {
    const int p = r & 1;
    f32x4 nu0 = cu[0], nu1 = cu[1], nu2 = cu[2], nu3 = cu[3];
    if (r < 15) {
      const float* up = ubase + (size_t)(2 * r + 2) * NU;
      nu0 = *(const f32x4*)up;        nu1 = *(const f32x4*)(up + 4);
      nu2 = *(const f32x4*)(up + 32); nu3 = *(const f32x4*)(up + 36);
    }
    s8v u0h, u0l, u1h, u1l;
    split8(cu[0], cu[1], u0h, u0l);
    split8(cu[2], cu[3], u1h, u1l);
    s8v fXh[4], fXl[4];
    #pragma unroll
    for (int kt = 0; kt < 4; ++kt) {
      fXh[kt] = *(const s8v*)&Xh[p][m][kt * 32 + q * 8];
      fXl[kt] = *(const s8v*)&Xl[p][m][kt * 32 + q * 8];
    }
    #pragma unroll
    for (int t2 = 0; t2 < 2; ++t2) {
      f32x4 a0 = {0.f,0.f,0.f,0.f}, a1 = {0.f,0.f,0.f,0.f}, a2 = {0.f,0.f,0.f,0.f};
      #pragma unroll
      for (int kt = 0; kt < 4; ++kt) a0 = mfma16(fXh[kt], fA2h[t2][kt], a0);
      a0 = mfma16(u0h, fABh[t2], a0);
      a0 = mfma16(u1h, fBh[t2],  a0);
      #pragma unroll
      for (int kt = 0; kt < 4; ++kt) a1 = mfma16(fXl[kt], fA2h[t2][kt], a1);
      a1 = mfma16(u0l, fABh[t2], a1);
      a1 = mfma16(u1l, fBh[t2],  a1);
      #pragma unroll
      for (int kt = 0; kt < 4; ++kt) a2 = mfma16(fXh[kt], fA2l[t2][kt], a2);
      a2 = mfma16(u0h, fABl[t2], a2);
      a2 = mfma16(u1h, fBl[t2],  a2);
      acc[t2] = a0 + a1 + a2;
    }
    if (r < 15) {
      #pragma unroll
      for (int t2 = 0; t2 < 2; ++t2) {
        const int col = (2 * w + t2) * 16 + m;
        #pragma unroll
        for (int rr = 0; rr < 4; ++rr) {
          unsigned short h, lo;
          split_trunc(acc[t2][rr], h, lo);
          Xh[1 - p][q * 4 + rr][col] = h;
          Xl[1 - p][q * 4 + rr][col] = lo;
        }
      }
      __syncthreads();
      cu[0] = nu0; cu[1] = nu1; cu[2] = nu2; cu[3] = nu3;
    }
  }
  // v = X_32 exact from accumulators
  #pragma unroll
  for (int t2 = 0; t2 < 2; ++t2) {
    const int col = (2 * w + t2) * 16 + m;
    #pragma unroll
    for (int rr = 0; rr < 4; ++rr) {
      const int row = g * 16 + q * 4 + rr;
      vout[(size_t)row * 128 + col] = acc[t2][rr];
    }
  }
}

// ---------------- carry: s_c = v_{c-1} + A^32 v_{c-2} + A^64 v_{c-3} + A^96 v_{c-4} ----------------
__global__ __launch_bounds__(256, 1) void k_carry(
    const unsigned short* __restrict__ G1h, const unsigned short* __restrict__ G1l,
    const unsigned short* __restrict__ G2h, const unsigned short* __restrict__ G2l,
    const unsigned short* __restrict__ G3h, const unsigned short* __restrict__ G3l,
    const float* __restrict__ v, float* __restrict__ sout) {
  const int tid = threadIdx.x;
  const int w = tid >> 6, l = tid & 63, q = l >> 4, m = l & 15;
  const int g = blockIdx.x;
  const int chm = g * 16 + m, cm = chm & (CPB - 1);

  f32x4 a[2];
  a[0] = (f32x4){0.f,0.f,0.f,0.f};
  a[1] = (f32x4){0.f,0.f,0.f,0.f};

#define CARRY_TERM(GH, GL, DELTA)                                              \
  {                                                                            \
    const s8v zero = {0,0,0,0,0,0,0,0};                                        \
    s8v vh[4], vl[4];                                                          \
    _Pragma("unroll")                                                          \
    for (int kt = 0; kt < 4; ++kt) {                                           \
      if (cm >= DELTA) {                                                       \
        const float* vp = v + (size_t)(chm - DELTA) * NX + kt * 32 + q * 8;    \
        split8(*(const f32x4*)vp, *(const f32x4*)(vp + 4), vh[kt], vl[kt]);    \
      } else { vh[kt] = zero; vl[kt] = zero; }                                 \
    }                                                                          \
    _Pragma("unroll")                                                          \
    for (int t2 = 0; t2 < 2; ++t2) {                                           \
      const int n = (2 * w + t2) * 16 + m;                                     \
      _Pragma("unroll")                                                        \
      for (int kt = 0; kt < 4; ++kt) {                                         \
        const int k0 = kt * 32 + q * 8;                                        \
        s8v gh = *(const s8v*)(GH + n * NX + k0);                              \
        s8v gl = *(const s8v*)(GL + n * NX + k0);                              \
        a[t2] = mfma16(vh[kt], gh, a[t2]);                                     \
        a[t2] = mfma16(vl[kt], gh, a[t2]);                                     \
        a[t2] = mfma16(vh[kt], gl, a[t2]);                                     \
      }                                                                        \
    }                                                                          \
  }

  CARRY_TERM(G1h, G1l, 2)
  CARRY_TERM(G2h, G2l, 3)
  CARRY_TERM(G3h, G3l, 4)
#undef CARRY_TERM

  #pragma unroll
  for (int t2 = 0; t2 < 2; ++t2) {
    const int col = (2 * w + t2) * 16 + m;
    #pragma unroll
    for (int rr = 0; rr < 4; ++rr) {
      const int chr = g * 16 + q * 4 + rr, cr = chr & (CPB - 1);
      float sv = 0.f;
      if (cr >= 1) sv = a[t2][rr] + v[(size_t)(chr - 1) * NX + col];
      sout[(size_t)chr * NX + col] = sv;
    }
  }
}

// ---------------- pass 2 (even): re-scan from s, write even x states ----------------
__global__ __launch_bounds__(256, 2) void k_pass2e(
    const float* __restrict__ d, const float* __restrict__ s,
    const unsigned short* __restrict__ A2h, const unsigned short* __restrict__ A2l,
    const unsigned short* __restrict__ ABh, const unsigned short* __restrict__ ABl,
    const unsigned short* __restrict__ Bh,  const unsigned short* __restrict__ Bl,
    float* __restrict__ xout) {
  __shared__ unsigned short Xh[2][16][LPAD];
  __shared__ unsigned short Xl[2][16][LPAD];
  const int tid = threadIdx.x;
  const int w = tid >> 6, l = tid & 63, q = l >> 4, m = l & 15;
  const int g = blockIdx.x;

  s8v fA2h[2][4], fA2l[2][4], fABh[2], fABl[2], fBh[2], fBl[2];
  #pragma unroll
  for (int t2 = 0; t2 < 2; ++t2) {
    const int n = (2 * w + t2) * 16 + m;
    #pragma unroll
    for (int kt = 0; kt < 4; ++kt) {
      const int k0 = kt * 32 + q * 8;
      fA2h[t2][kt] = *(const s8v*)(A2h + n * 128 + k0);
      fA2l[t2][kt] = *(const s8v*)(A2l + n * 128 + k0);
    }
    fABh[t2] = *(const s8v*)(ABh + n * 32 + q * 8);
    fABl[t2] = *(const s8v*)(ABl + n * 32 + q * 8);
    fBh[t2]  = *(const s8v*)(Bh  + n * 32 + q * 8);
    fBl[t2]  = *(const s8v*)(Bl  + n * 32 + q * 8);
  }

  // init: X_0 = s -> LDS buf0, and write x at j0 = chunk*CH (exact fp32 s)
  {
    const int lb = tid >> 4, i0 = (tid & 15) * 8;
    const int chS = g * 16 + lb, bS = chS >> 7, cS = chS & (CPB - 1);
    const float* sp = s + (size_t)chS * 128 + i0;
    f32x4 s0 = *(const f32x4*)sp, s1 = *(const f32x4*)(sp + 4);
    s8v hh, ll;
    split8(s0, s1, hh, ll);
    *(s8v*)&Xh[0][lb][i0] = hh;
    *(s8v*)&Xl[0][lb][i0] = ll;
    float* xp = xout + ((size_t)bS * (NN + 1) + (size_t)cS * CH) * NX + i0;
    *(f32x4*)xp = s0;
    *(f32x4*)(xp + 4) = s1;
  }
  __syncthreads();

  const int ch = g * 16 + m, b = ch >> 7, chunk = ch & (CPB - 1);
  const float* ubase = d + ((size_t)b * NN + chunk * CH) * NU + q * 8;

  // per-(t2,rr) x pointers (even states, starting at j = chunk*CH + 2)
  float* xptr[2][4];
  bool xlast[2][4];
  #pragma unroll
  for (int t2 = 0; t2 < 2; ++t2) {
    const int col = (2 * w + t2) * 16 + m;
    #pragma unroll
    for (int rr = 0; rr < 4; ++rr) {
      const int chX = g * 16 + q * 4 + rr, bX = chX >> 7, cX = chX & (CPB - 1);
      xptr[t2][rr] = xout + ((size_t)bX * (NN + 1) + (size_t)cX * CH + 2) * NX + col;
      xlast[t2][rr] = (cX == CPB - 1);
    }
  }

  f32x4 cu[4];
  cu[0] = *(const f32x4*)(ubase);      cu[1] = *(const f32x4*)(ubase + 4);
  cu[2] = *(const f32x4*)(ubase + 32); cu[3] = *(const f32x4*)(ubase + 36);

  #pragma unroll 2
  for (int r = 0; r < 16; ++r) {
    const int p = r & 1;
    f32x4 nu0 = cu[0], nu1 = cu[1], nu2 = cu[2], nu3 = cu[3];
    if (r < 15) {
      const float* up = ubase + (size_t)(2 * r + 2) * NU;
      nu0 = *(const f32x4*)up;        nu1 = *(const f32x4*)(up + 4);
      nu2 = *(const f32x4*)(up + 32); nu3 = *(const f32x4*)(up + 36);
    }
    s8v u0h, u0l, u1h, u1l;
    split8(cu[0], cu[1], u0h, u0l);
    split8(cu[2], cu[3], u1h, u1l);
    s8v fXh[4], fXl[4];
    #pragma unroll
    for (int kt = 0; kt < 4; ++kt) {
      fXh[kt] = *(const s8v*)&Xh[p][m][kt * 32 + q * 8];
      fXl[kt] = *(const s8v*)&Xl[p][m][kt * 32 + q * 8];
    }
    f32x4 acc[2];
    #pragma unroll
    for (int t2 = 0; t2 < 2; ++t2) {
      f32x4 a0 = {0.f,0.f,0.f,0.f}, a1 = {0.f,0.f,0.f,0.f}, a2 = {0.f,0.f,0.f,0.f};
      #pragma unroll
      for (int kt = 0; kt < 4; ++kt) a0 = mfma16(fXh[kt], fA2h[t2][kt], a0);
      a0 = mfma16(u0h, fABh[t2], a0);
      a0 = mfma16(u1h, fBh[t2],  a0);
      #pragma unroll
      for (int kt = 0; kt < 4; ++kt) a1 = mfma16(fXl[kt], fA2h[t2][kt], a1);
      a1 = mfma16(u0l, fABh[t2], a1);
      a1 = mfma16(u1l, fBh[t2],  a1);
      #pragma unroll
      for (int kt = 0; kt < 4; ++kt) a2 = mfma16(fXh[kt], fA2l[t2][kt], a2);
      a2 = mfma16(u0h, fABl[t2], a2);
      a2 = mfma16(u1h, fBl[t2],  a2);
      acc[t2] = a0 + a1 + a2;
    }

    // store even state j = chunk*CH + 2r + 2 (skip boundary except final)
    #pragma unroll
    for (int t2 = 0; t2 < 2; ++t2) {
      #pragma unroll
      for (int rr = 0; rr < 4; ++rr) {
        if (r < 15 || xlast[t2][rr]) *(xptr[t2][rr]) = acc[t2][rr];
      }
    }

    if (r < 15) {
      #pragma unroll
      for (int t2 = 0; t2 < 2; ++t2) {
        const int col = (2 * w + t2) * 16 + m;
        #pragma unroll
        for (int rr = 0; rr < 4; ++rr) {
          unsigned short h, lo;
          split_trunc(acc[t2][rr], h, lo);
          Xh[1 - p][q * 4 + rr][col] = h;
          Xl[1 - p][q * 4 + rr][col] = lo;
        }
      }
      __syncthreads();
      cu[0] = nu0; cu[1] = nu1; cu[2] = nu2; cu[3] = nu3;
      #pragma unroll
      for (int t2 = 0; t2 < 2; ++t2)
        #pragma unroll
        for (int rr = 0; rr < 4; ++rr) xptr[t2][rr] += 2 * NX;
    }
  }
}

// ---------------- odd states + all y: fully parallel, no scan ----------------
// x_{2e+1} = A x_{2e} + B u_{2e};  y_{2e} = C x_{2e} + D u_{2e};  y_{2e+1} = C x_{2e+1} + D u_{2e+1}
__global__ __launch_bounds__(256, 2) void k_oddy(
    const float* __restrict__ d, const float* __restrict__ xin,
    const unsigned short* __restrict__ Ah, const unsigned short* __restrict__ Al,
    const unsigned short* __restrict__ Bh, const unsigned short* __restrict__ Bl,
    const unsigned short* __restrict__ Ch, const unsigned short* __restrict__ Cl,
    const unsigned short* __restrict__ Dh, const unsigned short* __restrict__ Dl,
    float* __restrict__ yout, float* __restrict__ xout) {
  __shared__ unsigned short Xoh[16][LPAD];
  __shared__ unsigned short Xol[16][LPAD];
  const int tid = threadIdx.x;
  const int w = tid >> 6, l = tid & 63, q = l >> 4, m = l & 15;
  const int g = blockIdx.x;                 // 8192 blocks
  const int b = g >> 7, e0 = (g & 127) * 16;  // 16 even-steps per block

  // constant fragments: A,B for x_odd; C,D for this wave's y-tile
  s8v fAh[2][4], fAl[2][4], fBh[2], fBl[2];
  #pragma unroll
  for (int t2 = 0; t2 < 2; ++t2) {
    const int n = (2 * w + t2) * 16 + m;
    #pragma unroll
    for (int kt = 0; kt < 4; ++kt) {
      const int k0 = kt * 32 + q * 8;
      fAh[t2][kt] = *(const s8v*)(Ah + n * 128 + k0);
      fAl[t2][kt] = *(const s8v*)(Al + n * 128 + k0);
    }
    fBh[t2] = *(const s8v*)(Bh + n * 32 + q * 8);
    fBl[t2] = *(const s8v*)(Bl + n * 32 + q * 8);
  }
  const int yt = w & 1;                     // y-tile (ny cols yt*16..yt*16+15)
  s8v fCh[4], fCl[4], fDh, fDl;
  {
    const int o = yt * 16 + m;
    #pragma unroll
    for (int kt = 0; kt < 4; ++kt) {
      const int k0 = kt * 32 + q * 8;
      fCh[kt] = *(const s8v*)(Ch + o * 128 + k0);
      fCl[kt] = *(const s8v*)(Cl + o * 128 + k0);
    }
    fDh = *(const s8v*)(Dh + o * 32 + q * 8);
    fDl = *(const s8v*)(Dl + o * 32 + q * 8);
  }

  // x_even fragments (rows m), u fragments
  s8v fXh[4], fXl[4];
  const float* xb = xin + ((size_t)b * (NN + 1) + (size_t)2 * (e0 + m)) * NX;
  #pragma unroll
  for (int kt = 0; kt < 4; ++kt) {
    const int k0 = kt * 32 + q * 8;
    split8(*(const f32x4*)(xb + k0), *(const f32x4*)(xb + k0 + 4), fXh[kt], fXl[kt]);
  }
  const float* ub = d + ((size_t)b * NN + (size_t)2 * (e0 + m)) * NU + q * 8;
  s8v uEh, uEl;
  split8(*(const f32x4*)ub, *(const f32x4*)(ub + 4), uEh, uEl);
  s8v uOh = {0,0,0,0,0,0,0,0}, uOl = {0,0,0,0,0,0,0,0};
  if (w >= 2) {
    split8(*(const f32x4*)(ub + NU), *(const f32x4*)(ub + NU + 4), uOh, uOl);
  }

  // x_odd = A x_even + B u_even (3-term), cols (2w+t2)*16+m
  f32x4 xo[2];
  #pragma unroll
  for (int t2 = 0; t2 < 2; ++t2) {
    f32x4 a0 = {0.f,0.f,0.f,0.f}, a1 = {0.f,0.f,0.f,0.f}, a2 = {0.f,0.f,0.f,0.f};
    #pragma unroll
    for (int kt = 0; kt < 4; ++kt) a0 = mfma16(fXh[kt], fAh[t2][kt], a0);
    a0 = mfma16(uEh, fBh[t2], a0);
    #pragma unroll
    for (int kt = 0; kt < 4; ++kt) a1 = mfma16(fXl[kt], fAh[t2][kt], a1);
    a1 = mfma16(uEl, fBh[t2], a1);
    #pragma unroll
    for (int kt = 0; kt < 4; ++kt) a2 = mfma16(fXh[kt], fAl[t2][kt], a2);
    a2 = mfma16(uEh, fBl[t2], a2);
    xo[t2] = a0 + a1 + a2;
  }
  // store x_odd + stage hi/lo into LDS for y_odd
  #pragma unroll
  for (int t2 = 0; t2 < 2; ++t2) {
    const int col = (2 * w + t2) * 16 + m;
    #pragma unroll
    for (int rr = 0; rr < 4; ++rr) {
      const int e = e0 + q * 4 + rr;
      xout[((size_t)b * (NN + 1) + (size_t)(2 * e + 1)) * NX + col] = xo[t2][rr];
      unsigned short h, lo;
      split_trunc(xo[t2][rr], h, lo);
      Xoh[q * 4 + rr][col] = h;
      Xol[q * 4 + rr][col] = lo;
    }
  }
  __syncthreads();

  // y: waves 0,1 -> y_even from register x_even frags; waves 2,3 -> y_odd from LDS
  f32x4 yv;
  if (w < 2) {
    f32x4 b0 = {0.f,0.f,0.f,0.f}, b1 = {0.f,0.f,0.f,0.f}, b2 = {0.f,0.f,0.f,0.f};
    #pragma unroll
    for (int kt = 0; kt < 4; ++kt) b0 = mfma16(fXh[kt], fCh[kt], b0);
    b0 = mfma16(uEh, fDh, b0);
    #pragma unroll
    for (int kt = 0; kt < 4; ++kt) b1 = mfma16(fXl[kt], fCh[kt], b1);
    b1 = mfma16(uEl, fDh, b1);
    #pragma unroll
    for (int kt = 0; kt < 4; ++kt) b2 = mfma16(fXh[kt], fCl[kt], b2);
    b2 = mfma16(uEh, fDl, b2);
    yv = b0 + b1 + b2;
  } else {
    s8v fOh[4], fOl[4];
    #pragma unroll
    for (int kt = 0; kt < 4; ++kt) {
      fOh[kt] = *(const s8v*)&Xoh[m][kt * 32 + q * 8];
      fOl[kt] = *(const s8v*)&Xol[m][kt * 32 + q * 8];
    }
    f32x4 c0 = {0.f,0.f,0.f,0.f}, c1 = {0.f,0.f,0.f,0.f}, c2 = {0.f,0.f,0.f,0.f};
    #pragma unroll
    for (int kt = 0; kt < 4; ++kt) c0 = mfma16(fOh[kt], fCh[kt], c0);
    c0 = mfma16(uOh, fDh, c0);
    #pragma unroll
    for (int kt = 0; kt < 4; ++kt) c1 = mfma16(fOl[kt], fCh[kt], c1);
    c1 = mfma16(uOl, fDh, c1);
    #pragma unroll
    for (int kt = 0; kt < 4; ++kt) c2 = mfma16(fOh[kt], fCl[kt], c2);
    c2 = mfma16(uOh, fDl, c2);
    yv = c0 + c1 + c2;
  }
  const int yodd = (w >= 2) ? 1 : 0;
  #pragma unroll
  for (int rr = 0; rr < 4; ++rr) {
    const int e = e0 + q * 4 + rr;
    yout[((size_t)b * NN + (size_t)(2 * e + yodd)) * NY + yt * 16 + m] = yv[rr];
  }
}

// ---------------- launcher ----------------
extern "C" void kernel_launch(void* const* d_in, const int* in_sizes, int n_in,
                              void* d_out, int out_size, void* d_ws, size_t ws_size,
                              hipStream_t stream) {
  (void)in_sizes; (void)n_in; (void)out_size; (void)ws_size;
  const float* d = (const float*)d_in[0];
  const float* A = (const float*)d_in[1];
  const float* B = (const float*)d_in[2];
  const float* C = (const float*)d_in[3];
  const float* D = (const float*)d_in[4];

  char* ws = (char*)d_ws;
  unsigned short* Ah  = (unsigned short*)(ws + OFF_AH);
  unsigned short* Al  = (unsigned short*)(ws + OFF_AL);
  unsigned short* Bh  = (unsigned short*)(ws + OFF_BH);
  unsigned short* Bl  = (unsigned short*)(ws + OFF_BL);
  unsigned short* Chp = (unsigned short*)(ws + OFF_CH);
  unsigned short* Clp = (unsigned short*)(ws + OFF_CL);
  unsigned short* Dhp = (unsigned short*)(ws + OFF_DH);
  unsigned short* Dlp = (unsigned short*)(ws + OFF_DL);
  unsigned short* A2h = (unsigned short*)(ws + OFF_A2H);
  unsigned short* A2l = (unsigned short*)(ws + OFF_A2L);
  unsigned short* ABh = (unsigned short*)(ws + OFF_ABH);
  unsigned short* ABl = (unsigned short*)(ws + OFF_ABL);
  unsigned short* G1h = (unsigned short*)(ws + OFF_G1H);
  unsigned short* G1l = (unsigned short*)(ws + OFF_G1L);
  unsigned short* G2h = (unsigned short*)(ws + OFF_G2H);
  unsigned short* G2l = (unsigned short*)(ws + OFF_G2L);
  unsigned short* G3h = (unsigned short*)(ws + OFF_G3H);
  unsigned short* G3l = (unsigned short*)(ws + OFF_G3L);
  float* P0 = (float*)(ws + OFF_P0);
  float* P1 = (float*)(ws + OFF_P1);
  float* V  = (float*)(ws + OFF_V);
  float* S  = (float*)(ws + OFF_S);

  float* yout = (float*)d_out;
  float* xout = yout + (size_t)BATCH * NN * NY;

  k_mm_conv<<<164, 256, 0, stream>>>(A, B, C, D, P0, A2h, A2l,
                                     Ah, Al, Bh, Bl, Chp, Clp, Dhp, Dlp);   // A^2 + splits
  k_ab<<<16, 256, 0, stream>>>(A, B, ABh, ABl);
  k_mm128<<<64, 256, 0, stream>>>(P0, P0, P1, nullptr, nullptr, 0);         // A^4
  k_mm128<<<64, 256, 0, stream>>>(P1, P1, P0, nullptr, nullptr, 0);         // A^8
  k_mm128<<<64, 256, 0, stream>>>(P0, P0, P1, nullptr, nullptr, 0);         // A^16
  k_mm128<<<64, 256, 0, stream>>>(P1, P1, P0, G1h, G1l, 1);                 // A^32 (P0)
  k_mm128<<<64, 256, 0, stream>>>(P0, P0, P1, G2h, G2l, 1);                 // A^64 (P1)
  k_mm128<<<64, 256, 0, stream>>>(P0, P1, V,  G3h, G3l, 1);                 // A^96 (scratch V)

  k_pass1<<<512, 256, 0, stream>>>(d, A2h, A2l, ABh, ABl, Bh, Bl, V);
  k_carry<<<512, 256, 0, stream>>>(G1h, G1l, G2h, G2l, G3h, G3l, V, S);
  k_pass2e<<<512, 256, 0, stream>>>(d, S, A2h, A2l, ABh, ABl, Bh, Bl, xout);
  k_oddy<<<8192, 256, 0, stream>>>(d, xout, Ah, Al, Bh, Bl, Chp, Clp, Dhp, Dlp,
                                   yout, xout);
}

// Round 2
// 290.349 us; speedup vs baseline: 1.4309x; 1.4309x over previous
//
#include <hip/hip_runtime.h>
#include <stdint.h>
#include <stddef.h>

typedef short s8v   __attribute__((ext_vector_type(8)));  // 8 bf16 (4 VGPRs)
typedef float f32x4 __attribute__((ext_vector_type(4)));

union BF8 { s8v v; unsigned short u[8]; };

__device__ __forceinline__ float bf16_f(unsigned short h) {
  unsigned u = ((unsigned)h) << 16;
  return __builtin_bit_cast(float, u);
}
// truncation split: h = top16(x), residual exact (Sterbenz), l = top16(resid)
__device__ __forceinline__ void split_trunc(float x, unsigned short &h, unsigned short &l) {
  unsigned u = __builtin_bit_cast(unsigned, x);
  h = (unsigned short)(u >> 16);
  float hi = __builtin_bit_cast(float, u & 0xFFFF0000u);
  float r = x - hi;
  l = (unsigned short)(__builtin_bit_cast(unsigned, r) >> 16);
}
__device__ __forceinline__ f32x4 mfma16(s8v a, s8v b, f32x4 c) {
  return __builtin_amdgcn_mfma_f32_16x16x32_bf16(a, b, c, 0, 0, 0);
}
__device__ __forceinline__ void split8(f32x4 a, f32x4 b, s8v &h, s8v &l) {
  BF8 hh, ll;
  #pragma unroll
  for (int i = 0; i < 4; ++i) { split_trunc(a[i], hh.u[i], ll.u[i]); split_trunc(b[i], hh.u[4 + i], ll.u[4 + i]); }
  h = hh.v; l = ll.v;
}

#define BATCH 64
#define NN    4096
#define NX    128
#define NU    32
#define NY    32
#define LPAD  132   // LDS row stride in shorts (bank-conflict tuned)
#define CH    32    // chunk length
#define CPB   128   // chunks per batch

// ---------------- workspace byte offsets ----------------
#define OFF_AH   0
#define OFF_AL   32768
#define OFF_BH   65536
#define OFF_BL   73728
#define OFF_CH   81920
#define OFF_CL   90112
#define OFF_DH   98304
#define OFF_DL   100352
#define OFF_A2H  102400
#define OFF_A2L  135168
#define OFF_ABH  167936
#define OFF_ABL  176128
#define OFF_G1H  184320
#define OFF_G1L  217088
#define OFF_G2H  249856
#define OFF_G2L  282624
#define OFF_G3H  315392
#define OFF_G3L  348160
#define OFF_P0   380928
#define OFF_P1   446464
#define OFF_V    512000
#define OFF_S    4706304
// end 8900608 (~8.5 MB)

// ---------------- fused: A*A (fp32 + hi/lo) and split A,B,C,D ----------------
__global__ void k_mm_conv(const float* __restrict__ A, const float* __restrict__ B,
                          const float* __restrict__ C, const float* __restrict__ D,
                          float* __restrict__ P, unsigned short* A2h, unsigned short* A2l,
                          unsigned short* Ah, unsigned short* Al,
                          unsigned short* Bh, unsigned short* Bl,
                          unsigned short* Ch, unsigned short* Cl,
                          unsigned short* Dh, unsigned short* Dl) {
  int gid = blockIdx.x * 256 + threadIdx.x;
  if (blockIdx.x < 64) {               // A^2
    int row = gid >> 7, col = gid & 127;
    const float* xr = A + row * 128;
    float a0 = 0.f, a1 = 0.f;
    #pragma unroll 8
    for (int k = 0; k < 128; k += 2) {
      a0 = fmaf(xr[k],     A[k * 128 + col],       a0);
      a1 = fmaf(xr[k + 1], A[(k + 1) * 128 + col], a1);
    }
    float acc = a0 + a1;
    P[gid] = acc;
    unsigned short h, l; split_trunc(acc, h, l);
    A2h[gid] = h; A2l[gid] = l;
  } else {                             // convert
    int idx = gid - 16384;
    unsigned short h, l;
    if (idx < 16384)      { split_trunc(A[idx], h, l); Ah[idx] = h; Al[idx] = l; }
    else if (idx < 20480) { int i = idx - 16384; split_trunc(B[i], h, l); Bh[i] = h; Bl[i] = l; }
    else if (idx < 24576) { int i = idx - 20480; split_trunc(C[i], h, l); Ch[i] = h; Cl[i] = l; }
    else if (idx < 25600) { int i = idx - 24576; split_trunc(D[i], h, l); Dh[i] = h; Dl[i] = l; }
  }
}

// ---------------- 128x128 fp32 matmul (powers chain) ----------------
__global__ void k_mm128(const float* __restrict__ X, const float* __restrict__ Y,
                        float* __restrict__ Z, unsigned short* Zh, unsigned short* Zl,
                        int writeBF) {
  int gid = blockIdx.x * 256 + threadIdx.x;
  int row = gid >> 7, col = gid & 127;
  const float* xr = X + row * 128;
  float a0 = 0.f, a1 = 0.f;
  #pragma unroll 8
  for (int k = 0; k < 128; k += 2) {
    a0 = fmaf(xr[k],     Y[k * 128 + col],       a0);
    a1 = fmaf(xr[k + 1], Y[(k + 1) * 128 + col], a1);
  }
  float acc = a0 + a1;
  Z[gid] = acc;
  if (writeBF) { unsigned short h, l; split_trunc(acc, h, l); Zh[gid] = h; Zl[gid] = l; }
}

// ---------------- AB = A*B [128x32] (hi/lo) ----------------
__global__ void k_ab(const float* __restrict__ A, const float* __restrict__ B,
                     unsigned short* ABh, unsigned short* ABl) {
  int gid = blockIdx.x * 256 + threadIdx.x;   // 16 blocks -> 4096
  int row = gid >> 5, col = gid & 31;
  float acc = 0.f;
  #pragma unroll 8
  for (int k = 0; k < 128; ++k) acc = fmaf(A[row * 128 + k], B[k * 32 + col], acc);
  unsigned short h, l; split_trunc(acc, h, l);
  ABh[gid] = h; ABl[gid] = l;
}

// ---------------- pass 1: step-2 local chunk scans (x0=0) -> v_c = X_32 ----------------
__global__ __launch_bounds__(256, 2) void k_pass1(
    const float* __restrict__ d,
    const unsigned short* __restrict__ A2h, const unsigned short* __restrict__ A2l,
    const unsigned short* __restrict__ ABh, const unsigned short* __restrict__ ABl,
    const unsigned short* __restrict__ Bh,  const unsigned short* __restrict__ Bl,
    float* __restrict__ vout) {
  __shared__ unsigned short Xh[2][16][LPAD];
  __shared__ unsigned short Xl[2][16][LPAD];
  const int tid = threadIdx.x;
  const int w = tid >> 6, l = tid & 63, q = l >> 4, m = l & 15;
  const int g = blockIdx.x;

  s8v fA2h[2][4], fA2l[2][4], fABh[2], fABl[2], fBh[2], fBl[2];
  #pragma unroll
  for (int t2 = 0; t2 < 2; ++t2) {
    const int n = (2 * w + t2) * 16 + m;
    #pragma unroll
    for (int kt = 0; kt < 4; ++kt) {
      const int k0 = kt * 32 + q * 8;
      fA2h[t2][kt] = *(const s8v*)(A2h + n * 128 + k0);
      fA2l[t2][kt] = *(const s8v*)(A2l + n * 128 + k0);
    }
    fABh[t2] = *(const s8v*)(ABh + n * 32 + q * 8);
    fABl[t2] = *(const s8v*)(ABl + n * 32 + q * 8);
    fBh[t2]  = *(const s8v*)(Bh  + n * 32 + q * 8);
    fBl[t2]  = *(const s8v*)(Bl  + n * 32 + q * 8);
  }
  for (int i = tid; i < 16 * LPAD; i += 256) {
    ((unsigned short*)Xh[0])[i] = 0;
    ((unsigned short*)Xl[0])[i] = 0;
  }
  __syncthreads();

  const int ch = g * 16 + m, b = ch >> 7, chunk = ch & (CPB - 1);
  const float* ubase = d + ((size_t)b * NN + chunk * CH) * NU + q * 8;

  f32x4 cu[4];
  cu[0] = *(const f32x4*)(ubase);      cu[1] = *(const f32x4*)(ubase + 4);
  cu[2] = *(const f32x4*)(ubase + 32); cu[3] = *(const f32x4*)(ubase + 36);

  f32x4 acc[2];
  #pragma unroll 2
  for (int r = 0; r < 16; ++r) {
    const int p = r & 1;
    f32x4 nu0 = cu[0], nu1 = cu[1], nu2 = cu[2], nu3 = cu[3];
    if (r < 15) {
      const float* up = ubase + (size_t)(2 * r + 2) * NU;
      nu0 = *(const f32x4*)up;        nu1 = *(const f32x4*)(up + 4);
      nu2 = *(const f32x4*)(up + 32); nu3 = *(const f32x4*)(up + 36);
    }
    s8v u0h, u0l, u1h, u1l;
    split8(cu[0], cu[1], u0h, u0l);
    split8(cu[2], cu[3], u1h, u1l);
    s8v fXh[4], fXl[4];
    #pragma unroll
    for (int kt = 0; kt < 4; ++kt) {
      fXh[kt] = *(const s8v*)&Xh[p][m][kt * 32 + q * 8];
      fXl[kt] = *(const s8v*)&Xl[p][m][kt * 32 + q * 8];
    }
    #pragma unroll
    for (int t2 = 0; t2 < 2; ++t2) {
      f32x4 a0 = {0.f,0.f,0.f,0.f}, a1 = {0.f,0.f,0.f,0.f}, a2 = {0.f,0.f,0.f,0.f};
      #pragma unroll
      for (int kt = 0; kt < 4; ++kt) a0 = mfma16(fXh[kt], fA2h[t2][kt], a0);
      a0 = mfma16(u0h, fABh[t2], a0);
      a0 = mfma16(u1h, fBh[t2],  a0);
      #pragma unroll
      for (int kt = 0; kt < 4; ++kt) a1 = mfma16(fXl[kt], fA2h[t2][kt], a1);
      a1 = mfma16(u0l, fABh[t2], a1);
      a1 = mfma16(u1l, fBh[t2],  a1);
      #pragma unroll
      for (int kt = 0; kt < 4; ++kt) a2 = mfma16(fXh[kt], fA2l[t2][kt], a2);
      a2 = mfma16(u0h, fABl[t2], a2);
      a2 = mfma16(u1h, fBl[t2],  a2);
      acc[t2] = a0 + a1 + a2;
    }
    if (r < 15) {
      #pragma unroll
      for (int t2 = 0; t2 < 2; ++t2) {
        const int col = (2 * w + t2) * 16 + m;
        #pragma unroll
        for (int rr = 0; rr < 4; ++rr) {
          unsigned short h, lo;
          split_trunc(acc[t2][rr], h, lo);
          Xh[1 - p][q * 4 + rr][col] = h;
          Xl[1 - p][q * 4 + rr][col] = lo;
        }
      }
      __syncthreads();
      cu[0] = nu0; cu[1] = nu1; cu[2] = nu2; cu[3] = nu3;
    }
  }
  // v = X_32 exact from accumulators
  #pragma unroll
  for (int t2 = 0; t2 < 2; ++t2) {
    const int col = (2 * w + t2) * 16 + m;
    #pragma unroll
    for (int rr = 0; rr < 4; ++rr) {
      const int row = g * 16 + q * 4 + rr;
      vout[(size_t)row * 128 + col] = acc[t2][rr];
    }
  }
}

// ---------------- carry: s_c = v_{c-1} + A^32 v_{c-2} + A^64 v_{c-3} + A^96 v_{c-4} ----------------
__global__ __launch_bounds__(256, 1) void k_carry(
    const unsigned short* __restrict__ G1h, const unsigned short* __restrict__ G1l,
    const unsigned short* __restrict__ G2h, const unsigned short* __restrict__ G2l,
    const unsigned short* __restrict__ G3h, const unsigned short* __restrict__ G3l,
    const float* __restrict__ v, float* __restrict__ sout) {
  const int tid = threadIdx.x;
  const int w = tid >> 6, l = tid & 63, q = l >> 4, m = l & 15;
  const int g = blockIdx.x;
  const int chm = g * 16 + m, cm = chm & (CPB - 1);

  f32x4 a[2];
  a[0] = (f32x4){0.f,0.f,0.f,0.f};
  a[1] = (f32x4){0.f,0.f,0.f,0.f};

#define CARRY_TERM(GH, GL, DELTA)                                              \
  {                                                                            \
    const s8v zero = {0,0,0,0,0,0,0,0};                                        \
    s8v vh[4], vl[4];                                                          \
    _Pragma("unroll")                                                          \
    for (int kt = 0; kt < 4; ++kt) {                                           \
      if (cm >= DELTA) {                                                       \
        const float* vp = v + (size_t)(chm - DELTA) * NX + kt * 32 + q * 8;    \
        split8(*(const f32x4*)vp, *(const f32x4*)(vp + 4), vh[kt], vl[kt]);    \
      } else { vh[kt] = zero; vl[kt] = zero; }                                 \
    }                                                                          \
    _Pragma("unroll")                                                          \
    for (int t2 = 0; t2 < 2; ++t2) {                                           \
      const int n = (2 * w + t2) * 16 + m;                                     \
      _Pragma("unroll")                                                        \
      for (int kt = 0; kt < 4; ++kt) {                                         \
        const int k0 = kt * 32 + q * 8;                                        \
        s8v gh = *(const s8v*)(GH + n * NX + k0);                              \
        s8v gl = *(const s8v*)(GL + n * NX + k0);                              \
        a[t2] = mfma16(vh[kt], gh, a[t2]);                                     \
        a[t2] = mfma16(vl[kt], gh, a[t2]);                                     \
        a[t2] = mfma16(vh[kt], gl, a[t2]);                                     \
      }                                                                        \
    }                                                                          \
  }

  CARRY_TERM(G1h, G1l, 2)
  CARRY_TERM(G2h, G2l, 3)
  CARRY_TERM(G3h, G3l, 4)
#undef CARRY_TERM

  #pragma unroll
  for (int t2 = 0; t2 < 2; ++t2) {
    const int col = (2 * w + t2) * 16 + m;
    #pragma unroll
    for (int rr = 0; rr < 4; ++rr) {
      const int chr = g * 16 + q * 4 + rr, cr = chr & (CPB - 1);
      float sv = 0.f;
      if (cr >= 1) sv = a[t2][rr] + v[(size_t)(chr - 1) * NX + col];
      sout[(size_t)chr * NX + col] = sv;
    }
  }
}

// ---------------- pass 2 fused: A-only two-phase scan, writes all x and all y ----------------
// Per iter r (2 time steps):
//   phase A: x_odd = A x_even + B u0 ; y_even = C x_even + D u0 (waves 0,1)
//   phase B: x_even' = A x_odd + B u1 ; y_odd = C x_odd + D u1 (waves 2,3)
// No A^2/AB/CA/CB fragments needed -> ~236 VGPR -> 2 blocks/CU.
__global__ __launch_bounds__(256, 2) void k_scan2(
    const float* __restrict__ d, const float* __restrict__ s,
    const unsigned short* __restrict__ Ah, const unsigned short* __restrict__ Al,
    const unsigned short* __restrict__ Bh, const unsigned short* __restrict__ Bl,
    const unsigned short* __restrict__ Ch, const unsigned short* __restrict__ Cl,
    const unsigned short* __restrict__ Dh, const unsigned short* __restrict__ Dl,
    float* __restrict__ yout, float* __restrict__ xout) {
  __shared__ unsigned short Eh[16][LPAD];
  __shared__ unsigned short El[16][LPAD];
  __shared__ unsigned short Oh[16][LPAD];
  __shared__ unsigned short Ol[16][LPAD];
  const int tid = threadIdx.x;
  const int w = tid >> 6, l = tid & 63, q = l >> 4, m = l & 15;
  const int g = blockIdx.x;

  // A,B fragments (x recurrence), per wave: 2 col-tiles
  s8v fAh[2][4], fAl[2][4], fBh[2], fBl[2];
  #pragma unroll
  for (int t2 = 0; t2 < 2; ++t2) {
    const int n = (2 * w + t2) * 16 + m;
    #pragma unroll
    for (int kt = 0; kt < 4; ++kt) {
      const int k0 = kt * 32 + q * 8;
      fAh[t2][kt] = *(const s8v*)(Ah + n * 128 + k0);
      fAl[t2][kt] = *(const s8v*)(Al + n * 128 + k0);
    }
    fBh[t2] = *(const s8v*)(Bh + n * 32 + q * 8);
    fBl[t2] = *(const s8v*)(Bl + n * 32 + q * 8);
  }
  // C,D fragments: waves 0,1 -> y_even cols (w&1)*16.. ; waves 2,3 -> y_odd
  s8v fCh[4], fCl[4], fDh, fDl;
  {
    const int o = (w & 1) * 16 + m;
    #pragma unroll
    for (int kt = 0; kt < 4; ++kt) {
      const int k0 = kt * 32 + q * 8;
      fCh[kt] = *(const s8v*)(Ch + o * 128 + k0);
      fCl[kt] = *(const s8v*)(Cl + o * 128 + k0);
    }
    fDh = *(const s8v*)(Dh + o * 32 + q * 8);
    fDl = *(const s8v*)(Dl + o * 32 + q * 8);
  }

  // init: E = s (chunk start state), write x at j0 = chunk*CH (exact fp32)
  {
    const int lb = tid >> 4, i0 = (tid & 15) * 8;
    const int chS = g * 16 + lb, bS = chS >> 7, cS = chS & (CPB - 1);
    const float* sp = s + (size_t)chS * 128 + i0;
    f32x4 s0 = *(const f32x4*)sp, s1 = *(const f32x4*)(sp + 4);
    s8v hh, ll;
    split8(s0, s1, hh, ll);
    *(s8v*)&Eh[lb][i0] = hh;
    *(s8v*)&El[lb][i0] = ll;
    float* xp = xout + ((size_t)bS * (NN + 1) + (size_t)cS * CH) * NX + i0;
    *(f32x4*)xp = s0;
    *(f32x4*)(xp + 4) = s1;
  }
  __syncthreads();

  const int ch = g * 16 + m, b = ch >> 7, chunk = ch & (CPB - 1);
  const float* ubase = d + ((size_t)b * NN + chunk * CH) * NU + q * 8;

  // per-(t2,rr) x pointers at odd state j = chunk*CH + 1 ; even is +NX
  float* xptr[2][4];
  bool xlast[2][4];
  float* yptr[4];
  #pragma unroll
  for (int t2 = 0; t2 < 2; ++t2) {
    const int col = (2 * w + t2) * 16 + m;
    #pragma unroll
    for (int rr = 0; rr < 4; ++rr) {
      const int chX = g * 16 + q * 4 + rr, bX = chX >> 7, cX = chX & (CPB - 1);
      xptr[t2][rr] = xout + ((size_t)bX * (NN + 1) + (size_t)cX * CH + 1) * NX + col;
      xlast[t2][rr] = (cX == CPB - 1);
    }
  }
  #pragma unroll
  for (int rr = 0; rr < 4; ++rr) {
    const int chY = g * 16 + q * 4 + rr, bY = chY >> 7, cY = chY & (CPB - 1);
    yptr[rr] = yout + ((size_t)bY * NN + (size_t)cY * CH) * NY + (w & 1) * 16 + m;
  }

  f32x4 cu[4];
  cu[0] = *(const f32x4*)(ubase);      cu[1] = *(const f32x4*)(ubase + 4);
  cu[2] = *(const f32x4*)(ubase + 32); cu[3] = *(const f32x4*)(ubase + 36);

  #pragma unroll 1
  for (int r = 0; r < 16; ++r) {
    f32x4 nu0 = cu[0], nu1 = cu[1], nu2 = cu[2], nu3 = cu[3];
    if (r < 15) {
      const float* up = ubase + (size_t)(2 * r + 2) * NU;
      nu0 = *(const f32x4*)up;        nu1 = *(const f32x4*)(up + 4);
      nu2 = *(const f32x4*)(up + 32); nu3 = *(const f32x4*)(up + 36);
    }
    // ---- phase A: read even state, compute x_odd (+ y_even on waves 0,1) ----
    s8v u0h, u0l;
    split8(cu[0], cu[1], u0h, u0l);
    s8v fXh[4], fXl[4];
    #pragma unroll
    for (int kt = 0; kt < 4; ++kt) {
      fXh[kt] = *(const s8v*)&Eh[m][kt * 32 + q * 8];
      fXl[kt] = *(const s8v*)&El[m][kt * 32 + q * 8];
    }
    f32x4 xo[2];
    #pragma unroll
    for (int t2 = 0; t2 < 2; ++t2) {
      f32x4 a0 = {0.f,0.f,0.f,0.f}, a1 = {0.f,0.f,0.f,0.f}, a2 = {0.f,0.f,0.f,0.f};
      #pragma unroll
      for (int kt = 0; kt < 4; ++kt) a0 = mfma16(fXh[kt], fAh[t2][kt], a0);
      a0 = mfma16(u0h, fBh[t2], a0);
      #pragma unroll
      for (int kt = 0; kt < 4; ++kt) a1 = mfma16(fXl[kt], fAh[t2][kt], a1);
      a1 = mfma16(u0l, fBh[t2], a1);
      #pragma unroll
      for (int kt = 0; kt < 4; ++kt) a2 = mfma16(fXh[kt], fAl[t2][kt], a2);
      a2 = mfma16(u0h, fBl[t2], a2);
      xo[t2] = a0 + a1 + a2;
    }
    if (w < 2) {   // y_even = C x_even + D u0
      f32x4 b0 = {0.f,0.f,0.f,0.f}, b1 = {0.f,0.f,0.f,0.f}, b2 = {0.f,0.f,0.f,0.f};
      #pragma unroll
      for (int kt = 0; kt < 4; ++kt) b0 = mfma16(fXh[kt], fCh[kt], b0);
      b0 = mfma16(u0h, fDh, b0);
      #pragma unroll
      for (int kt = 0; kt < 4; ++kt) b1 = mfma16(fXl[kt], fCh[kt], b1);
      b1 = mfma16(u0l, fDh, b1);
      #pragma unroll
      for (int kt = 0; kt < 4; ++kt) b2 = mfma16(fXh[kt], fCl[kt], b2);
      b2 = mfma16(u0h, fDl, b2);
      f32x4 yv = b0 + b1 + b2;
      #pragma unroll
      for (int rr = 0; rr < 4; ++rr) *(yptr[rr]) = yv[rr];
    }
    // store x_odd (exact fp32) + stage hi/lo into O
    #pragma unroll
    for (int t2 = 0; t2 < 2; ++t2) {
      const int col = (2 * w + t2) * 16 + m;
      #pragma unroll
      for (int rr = 0; rr < 4; ++rr) {
        *(xptr[t2][rr]) = xo[t2][rr];
        unsigned short h, lo;
        split_trunc(xo[t2][rr], h, lo);
        Oh[q * 4 + rr][col] = h;
        Ol[q * 4 + rr][col] = lo;
      }
    }
    __syncthreads();

    // ---- phase B: read odd state, compute x_even' (+ y_odd on waves 2,3) ----
    s8v u1h, u1l;
    split8(cu[2], cu[3], u1h, u1l);
    s8v fOh[4], fOl[4];
    #pragma unroll
    for (int kt = 0; kt < 4; ++kt) {
      fOh[kt] = *(const s8v*)&Oh[m][kt * 32 + q * 8];
      fOl[kt] = *(const s8v*)&Ol[m][kt * 32 + q * 8];
    }
    f32x4 xe[2];
    #pragma unroll
    for (int t2 = 0; t2 < 2; ++t2) {
      f32x4 a0 = {0.f,0.f,0.f,0.f}, a1 = {0.f,0.f,0.f,0.f}, a2 = {0.f,0.f,0.f,0.f};
      #pragma unroll
      for (int kt = 0; kt < 4; ++kt) a0 = mfma16(fOh[kt], fAh[t2][kt], a0);
      a0 = mfma16(u1h, fBh[t2], a0);
      #pragma unroll
      for (int kt = 0; kt < 4; ++kt) a1 = mfma16(fOl[kt], fAh[t2][kt], a1);
      a1 = mfma16(u1l, fBh[t2], a1);
      #pragma unroll
      for (int kt = 0; kt < 4; ++kt) a2 = mfma16(fOh[kt], fAl[t2][kt], a2);
      a2 = mfma16(u1h, fBl[t2], a2);
      xe[t2] = a0 + a1 + a2;
    }
    if (w >= 2) {  // y_odd = C x_odd + D u1
      f32x4 c0 = {0.f,0.f,0.f,0.f}, c1 = {0.f,0.f,0.f,0.f}, c2 = {0.f,0.f,0.f,0.f};
      #pragma unroll
      for (int kt = 0; kt < 4; ++kt) c0 = mfma16(fOh[kt], fCh[kt], c0);
      c0 = mfma16(u1h, fDh, c0);
      #pragma unroll
      for (int kt = 0; kt < 4; ++kt) c1 = mfma16(fOl[kt], fCh[kt], c1);
      c1 = mfma16(u1l, fDh, c1);
      #pragma unroll
      for (int kt = 0; kt < 4; ++kt) c2 = mfma16(fOh[kt], fCl[kt], c2);
      c2 = mfma16(u1h, fDl, c2);
      f32x4 yv = c0 + c1 + c2;
      #pragma unroll
      for (int rr = 0; rr < 4; ++rr) *(yptr[rr] + NY) = yv[rr];
    }
    // store x_even' (skip chunk-boundary state except very last) + stage into E
    #pragma unroll
    for (int t2 = 0; t2 < 2; ++t2) {
      const int col = (2 * w + t2) * 16 + m;
      #pragma unroll
      for (int rr = 0; rr < 4; ++rr) {
        if (r < 15 || xlast[t2][rr]) *(xptr[t2][rr] + NX) = xe[t2][rr];
        unsigned short h, lo;
        split_trunc(xe[t2][rr], h, lo);
        Eh[q * 4 + rr][col] = h;
        El[q * 4 + rr][col] = lo;
      }
    }
    __syncthreads();

    if (r < 15) {
      cu[0] = nu0; cu[1] = nu1; cu[2] = nu2; cu[3] = nu3;
      #pragma unroll
      for (int t2 = 0; t2 < 2; ++t2)
        #pragma unroll
        for (int rr = 0; rr < 4; ++rr) xptr[t2][rr] += 2 * NX;
      #pragma unroll
      for (int rr = 0; rr < 4; ++rr) yptr[rr] += 2 * NY;
    }
  }
}

// ---------------- launcher ----------------
extern "C" void kernel_launch(void* const* d_in, const int* in_sizes, int n_in,
                              void* d_out, int out_size, void* d_ws, size_t ws_size,
                              hipStream_t stream) {
  (void)in_sizes; (void)n_in; (void)out_size; (void)ws_size;
  const float* d = (const float*)d_in[0];
  const float* A = (const float*)d_in[1];
  const float* B = (const float*)d_in[2];
  const float* C = (const float*)d_in[3];
  const float* D = (const float*)d_in[4];

  char* ws = (char*)d_ws;
  unsigned short* Ah  = (unsigned short*)(ws + OFF_AH);
  unsigned short* Al  = (unsigned short*)(ws + OFF_AL);
  unsigned short* Bh  = (unsigned short*)(ws + OFF_BH);
  unsigned short* Bl  = (unsigned short*)(ws + OFF_BL);
  unsigned short* Chp = (unsigned short*)(ws + OFF_CH);
  unsigned short* Clp = (unsigned short*)(ws + OFF_CL);
  unsigned short* Dhp = (unsigned short*)(ws + OFF_DH);
  unsigned short* Dlp = (unsigned short*)(ws + OFF_DL);
  unsigned short* A2h = (unsigned short*)(ws + OFF_A2H);
  unsigned short* A2l = (unsigned short*)(ws + OFF_A2L);
  unsigned short* ABh = (unsigned short*)(ws + OFF_ABH);
  unsigned short* ABl = (unsigned short*)(ws + OFF_ABL);
  unsigned short* G1h = (unsigned short*)(ws + OFF_G1H);
  unsigned short* G1l = (unsigned short*)(ws + OFF_G1L);
  unsigned short* G2h = (unsigned short*)(ws + OFF_G2H);
  unsigned short* G2l = (unsigned short*)(ws + OFF_G2L);
  unsigned short* G3h = (unsigned short*)(ws + OFF_G3H);
  unsigned short* G3l = (unsigned short*)(ws + OFF_G3L);
  float* P0 = (float*)(ws + OFF_P0);
  float* P1 = (float*)(ws + OFF_P1);
  float* V  = (float*)(ws + OFF_V);
  float* S  = (float*)(ws + OFF_S);

  float* yout = (float*)d_out;
  float* xout = yout + (size_t)BATCH * NN * NY;

  k_mm_conv<<<164, 256, 0, stream>>>(A, B, C, D, P0, A2h, A2l,
                                     Ah, Al, Bh, Bl, Chp, Clp, Dhp, Dlp);   // A^2 + splits
  k_ab<<<16, 256, 0, stream>>>(A, B, ABh, ABl);
  k_mm128<<<64, 256, 0, stream>>>(P0, P0, P1, nullptr, nullptr, 0);         // A^4
  k_mm128<<<64, 256, 0, stream>>>(P1, P1, P0, nullptr, nullptr, 0);         // A^8
  k_mm128<<<64, 256, 0, stream>>>(P0, P0, P1, nullptr, nullptr, 0);         // A^16
  k_mm128<<<64, 256, 0, stream>>>(P1, P1, P0, G1h, G1l, 1);                 // A^32 (P0)
  k_mm128<<<64, 256, 0, stream>>>(P0, P0, P1, G2h, G2l, 1);                 // A^64 (P1)
  k_mm128<<<64, 256, 0, stream>>>(P0, P1, V,  G3h, G3l, 1);                 // A^96 (scratch V)

  k_pass1<<<512, 256, 0, stream>>>(d, A2h, A2l, ABh, ABl, Bh, Bl, V);
  k_carry<<<512, 256, 0, stream>>>(G1h, G1l, G2h, G2l, G3h, G3l, V, S);
  k_scan2<<<512, 256, 0, stream>>>(d, S, Ah, Al, Bh, Bl, Chp, Clp, Dhp, Dlp,
                                   yout, xout);
}